// Round 3
// baseline (2062.420 us; speedup 1.0000x reference)
//
#include <hip/hip_runtime.h>
#include <hip/hip_bf16.h>

// Problem: B=8192, D=768, L=16384, K=100. ALL I/O fp32.
// out = [latents_pre_act (B*L) | latents (B*L) | recons (B*D)] fp32 concat.
//
//  k1: per-row mean/std, xn=(x-mu)/(std+eps)-pre_bias; write fp32 xn32 and
//      hi/lo bf16 split
//  k2: transpose W_enc [D,L] -> Wt32 [L,D] fp32 + Wh/Wl bf16 split
//  k3: MFMA GEMM, 3-term hi/lo product (sigma ~ 4e-6), 128x128x32 tiles,
//      global_load_lds(16B); fp32 pre-acts straight to out0
//  k4: top-k with exact boundary resolution: bisection on monotone uint keys
//      gives approx kth; values > kth+W are certainly in (A <= 99), values in
//      [kth-W, kth+W] (expected ~1-2) are re-derived as exact f64 dots and
//      ranked (ties -> lower index). Then scatter latents + fused decode.

#define Bdim 8192
#define Ddim 768
#define Ldim 16384
#define Kdim 100
#define BAND_W 1.5e-4f
#define BAND_MAX 64

typedef short s16x8 __attribute__((ext_vector_type(8)));
typedef float f32x4 __attribute__((ext_vector_type(4)));

__device__ inline float key2float(unsigned int k) {
  unsigned int u = (k & 0x80000000u) ? (k & 0x7fffffffu) : ~k;
  return __uint_as_float(u);
}

// ---------------------------------------------------------------- normalize
__global__ __launch_bounds__(256) void normalize_kernel(
    const float* __restrict__ x, const float* __restrict__ pre_bias,
    __hip_bfloat16* __restrict__ xh, __hip_bfloat16* __restrict__ xl,
    float* __restrict__ xn32, float* __restrict__ mu_out, float* __restrict__ std_out) {
  const int r = blockIdx.x, t = threadIdx.x;
  const int lane = t & 63, wid = t >> 6;
  const float* xr = x + (size_t)r * Ddim;
  float v0 = xr[t], v1 = xr[t + 256], v2 = xr[t + 512];
  __shared__ float sred[4];
  float s = v0 + v1 + v2;
  for (int off = 32; off > 0; off >>= 1) s += __shfl_down(s, off, 64);
  if (lane == 0) sred[wid] = s;
  __syncthreads();
  float mu = (sred[0] + sred[1] + sred[2] + sred[3]) * (1.0f / 768.0f);
  __syncthreads();
  float d0 = v0 - mu, d1 = v1 - mu, d2 = v2 - mu;
  s = d0 * d0 + d1 * d1 + d2 * d2;
  for (int off = 32; off > 0; off >>= 1) s += __shfl_down(s, off, 64);
  if (lane == 0) sred[wid] = s;
  __syncthreads();
  float var = (sred[0] + sred[1] + sred[2] + sred[3]) * (1.0f / 768.0f);
  float sd = sqrtf(var);
  float inv = 1.0f / (sd + 1e-5f);
  size_t base = (size_t)r * Ddim;
  #pragma unroll
  for (int j = 0; j < 3; ++j) {
    int c = t + j * 256;
    float d = (j == 0 ? d0 : (j == 1 ? d1 : d2));
    float sn = d * inv - pre_bias[c];
    __hip_bfloat16 hi = __float2bfloat16(sn);
    float lo = sn - __bfloat162float(hi);
    xn32[base + c] = sn;
    xh[base + c] = hi;
    xl[base + c] = __float2bfloat16(lo);
  }
  if (t == 0) { mu_out[r] = mu; std_out[r] = sd; }
}

// ------------------------------------------------------- W transpose + split
__global__ __launch_bounds__(256) void wsplit_kernel(
    const float* __restrict__ W, __hip_bfloat16* __restrict__ Wh,
    __hip_bfloat16* __restrict__ Wl, float* __restrict__ Wt32) {
  __shared__ float tile[32][33];
  const int tx = threadIdx.x & 31, ty = threadIdx.x >> 5;
  const int l0 = blockIdx.x * 32, d0 = blockIdx.y * 32;
  #pragma unroll
  for (int i = ty; i < 32; i += 8)
    tile[i][tx] = W[(size_t)(d0 + i) * Ldim + l0 + tx];
  __syncthreads();
  #pragma unroll
  for (int i = ty; i < 32; i += 8) {
    float v = tile[tx][i];  // = W[d0+tx][l0+i]
    __hip_bfloat16 h = __float2bfloat16(v);
    float lo = v - __bfloat162float(h);
    const size_t off = (size_t)(l0 + i) * Ddim + d0 + tx;
    Wh[off] = h;
    Wl[off] = __float2bfloat16(lo);
    Wt32[off] = v;
  }
}

// ---------------------------------------------------------------- encode GEMM
// C[M=8192,N=16384] = (Ah+Al)[M,768] @ (Wh+Wl)^T ; W* is [N,768] k-contiguous.
// 3-term: ah*bh + al*bh + ah*bl  (al*bl dropped)
__global__ __launch_bounds__(256, 2) void encode_gemm_kernel(
    const __hip_bfloat16* __restrict__ xh, const __hip_bfloat16* __restrict__ xl,
    const __hip_bfloat16* __restrict__ wh, const __hip_bfloat16* __restrict__ wl,
    const float* __restrict__ lb, float* __restrict__ out0) {
  __shared__ __align__(16) __hip_bfloat16 sAh[128 * 32];
  __shared__ __align__(16) __hip_bfloat16 sAl[128 * 32];
  __shared__ __align__(16) __hip_bfloat16 sBh[128 * 32];
  __shared__ __align__(16) __hip_bfloat16 sBl[128 * 32];
  const int t = threadIdx.x;
  const int wid = t >> 6, lane = t & 63;
  const int quad = lane >> 4, lr = lane & 15;
  const int m0 = blockIdx.y * 128, n0 = blockIdx.x * 128;
  const int wm = (wid >> 1) * 64, wn = (wid & 1) * 64;

  f32x4 acc[4][4];
  #pragma unroll
  for (int i = 0; i < 4; ++i)
    #pragma unroll
    for (int j = 0; j < 4; ++j) acc[i][j] = (f32x4){0.f, 0.f, 0.f, 0.f};

  const int srow = lane >> 2;       // 16 rows per 1 KiB load
  const int scol = (lane & 3) * 8;  // 4 lanes x 8 elem (16 B) per row

  for (int kt = 0; kt < Ddim / 32; ++kt) {
    const int k0 = kt * 32;
    #pragma unroll
    for (int j = 0; j < 2; ++j) {
      const int c = wid * 2 + j;  // chunk 0..7, 16 rows each
      const int row = c * 16 + srow;
      const __hip_bfloat16* ga = xh + (size_t)(m0 + row) * Ddim + k0 + scol;
      const __hip_bfloat16* gb = xl + (size_t)(m0 + row) * Ddim + k0 + scol;
      const __hip_bfloat16* gc = wh + (size_t)(n0 + row) * Ddim + k0 + scol;
      const __hip_bfloat16* gd = wl + (size_t)(n0 + row) * Ddim + k0 + scol;
      __builtin_amdgcn_global_load_lds(
          (const __attribute__((address_space(1))) void*)ga,
          (__attribute__((address_space(3))) void*)(sAh + c * 512), 16, 0, 0);
      __builtin_amdgcn_global_load_lds(
          (const __attribute__((address_space(1))) void*)gb,
          (__attribute__((address_space(3))) void*)(sAl + c * 512), 16, 0, 0);
      __builtin_amdgcn_global_load_lds(
          (const __attribute__((address_space(1))) void*)gc,
          (__attribute__((address_space(3))) void*)(sBh + c * 512), 16, 0, 0);
      __builtin_amdgcn_global_load_lds(
          (const __attribute__((address_space(1))) void*)gd,
          (__attribute__((address_space(3))) void*)(sBl + c * 512), 16, 0, 0);
    }
    asm volatile("s_waitcnt vmcnt(0)" ::: "memory");
    __syncthreads();

    const int koff = quad * 8;
    s16x8 ah[4], al[4], bh[4], bl[4];
    #pragma unroll
    for (int nt = 0; nt < 4; ++nt) {
      bh[nt] = *(const s16x8*)&sBh[(wn + nt * 16 + lr) * 32 + koff];
      bl[nt] = *(const s16x8*)&sBl[(wn + nt * 16 + lr) * 32 + koff];
    }
    #pragma unroll
    for (int mt = 0; mt < 4; ++mt) {
      ah[mt] = *(const s16x8*)&sAh[(wm + mt * 16 + lr) * 32 + koff];
      al[mt] = *(const s16x8*)&sAl[(wm + mt * 16 + lr) * 32 + koff];
    }
    #pragma unroll
    for (int mt = 0; mt < 4; ++mt)
      #pragma unroll
      for (int nt = 0; nt < 4; ++nt) {
        acc[mt][nt] = __builtin_amdgcn_mfma_f32_16x16x32_bf16(
            ah[mt], bh[nt], acc[mt][nt], 0, 0, 0);
        acc[mt][nt] = __builtin_amdgcn_mfma_f32_16x16x32_bf16(
            al[mt], bh[nt], acc[mt][nt], 0, 0, 0);
        acc[mt][nt] = __builtin_amdgcn_mfma_f32_16x16x32_bf16(
            ah[mt], bl[nt], acc[mt][nt], 0, 0, 0);
      }
    __syncthreads();
  }

  #pragma unroll
  for (int nt = 0; nt < 4; ++nt) {
    const int n = n0 + wn + nt * 16 + lr;
    const float bias = lb[n];
    #pragma unroll
    for (int mt = 0; mt < 4; ++mt) {
      const int mbase = m0 + wm + mt * 16 + quad * 4;
      #pragma unroll
      for (int rg = 0; rg < 4; ++rg)
        out0[(size_t)(mbase + rg) * Ldim + n] = acc[mt][nt][rg] + bias;
    }
  }
}

// ---------------------------------------------------------------- topk+decode
__global__ __launch_bounds__(256) void topk_decode_kernel(
    const float* __restrict__ pre, const float* __restrict__ xn32,
    const float* __restrict__ Wt32, const float* __restrict__ lb,
    const float* __restrict__ Wdec, const float* __restrict__ pre_bias,
    const float* __restrict__ mu_arr, const float* __restrict__ std_arr,
    float* __restrict__ out_lat, float* __restrict__ out_rec) {
  const int r = blockIdx.x, t = threadIdx.x;
  const int lane = t & 63, wid = t >> 6;
  const float* row = pre + (size_t)r * Ldim;

  unsigned int keys[64];
  #pragma unroll
  for (int j = 0; j < 64; ++j) {
    unsigned int u = __float_as_uint(row[t + j * 256]);
    keys[j] = (u & 0x80000000u) ? ~u : (u | 0x80000000u);
  }

  __shared__ int sred[4];
  __shared__ int s_gt, s_band;
  __shared__ int sel_idx[128];
  __shared__ float sel_val[128];
  __shared__ int band_idx[BAND_MAX];
  __shared__ double band_rv[BAND_MAX];   // f64 dot + bias (rank key)
  __shared__ float band_ov[BAND_MAX];    // fp32 output value
  __shared__ float sxn[Ddim];

  // 32-step bisection: kth = K-th largest key (exact on approx values)
  unsigned int kth = 0u;
  for (int bit = 31; bit >= 0; --bit) {
    const unsigned int cand = kth | (1u << bit);
    int c = 0;
    #pragma unroll
    for (int j = 0; j < 64; ++j) c += (keys[j] >= cand) ? 1 : 0;
    for (int off = 32; off > 0; off >>= 1) c += __shfl_down(c, off, 64);
    if (lane == 0) sred[wid] = c;
    __syncthreads();
    const int tot = sred[0] + sred[1] + sred[2] + sred[3];
    __syncthreads();
    if (tot >= Kdim) kth = cand;
  }

  const float kv = key2float(kth);
  const float Thi = kv + BAND_W, Tlo = kv - BAND_W;

  if (t == 0) { s_gt = 0; s_band = 0; }
  // stage xn row while we're at it
  sxn[t] = xn32[(size_t)r * Ddim + t];
  sxn[t + 256] = xn32[(size_t)r * Ddim + t + 256];
  sxn[t + 512] = xn32[(size_t)r * Ddim + t + 512];
  __syncthreads();

  #pragma unroll
  for (int j = 0; j < 64; ++j) {
    const float v = key2float(keys[j]);
    if (v > Thi) {
      const int p = atomicAdd(&s_gt, 1);
      sel_idx[p] = t + j * 256;
      sel_val[p] = v;
    } else if (v >= Tlo) {
      const int p = atomicAdd(&s_band, 1);
      if (p < BAND_MAX) band_idx[p] = t + j * 256;
    }
  }
  __syncthreads();

  const int A = s_gt;                       // certainly in top-K (<= 99)
  const int m = min(s_band, BAND_MAX);      // uncertain band (expected ~1-2)
  const int need = Kdim - A;                // 1..m slots to fill from band

  // exact f64 re-derivation of band members (one wave per candidate)
  for (int c = wid; c < m; c += 4) {
    const int ci = band_idx[c];
    const float* wr = Wt32 + (size_t)ci * Ddim;
    double s = 0.0;
    #pragma unroll
    for (int j = 0; j < 12; ++j) {
      const int e = lane + j * 64;
      s += (double)sxn[e] * (double)wr[e];
    }
    for (int off = 32; off > 0; off >>= 1) s += __shfl_down(s, off, 64);
    if (lane == 0) {
      band_rv[c] = s + (double)lb[ci];
      band_ov[c] = (float)s + lb[ci];   // np op order: fp32(dot) + bias
    }
  }
  __syncthreads();

  // rank band members (desc value, ties -> lower index); top `need` join sel
  if (t < m) {
    const double mine = band_rv[t];
    const int myi = band_idx[t];
    int rank = 0;
    for (int j = 0; j < m; ++j) {
      if (band_rv[j] > mine || (band_rv[j] == mine && band_idx[j] < myi)) ++rank;
    }
    if (rank < need) {
      const int p = atomicAdd(&s_gt, 1);
      sel_idx[p] = myi;
      sel_val[p] = band_ov[t];
    }
  }
  __syncthreads();
  // now sel_* holds exactly Kdim entries

  // output 1: zero the row, scatter the kept values
  float* lat = out_lat + (size_t)r * Ldim;
  float4 z; z.x = 0.f; z.y = 0.f; z.z = 0.f; z.w = 0.f;
  float4* lp = (float4*)lat;
  #pragma unroll
  for (int j = 0; j < 16; ++j) lp[t + j * 256] = z;
  __syncthreads();
  if (t < Kdim) lat[sel_idx[t]] = sel_val[t];

  // output 2: sparse decode + denormalize
  float a0 = 0.f, a1 = 0.f, a2 = 0.f;
  for (int j = 0; j < Kdim; ++j) {
    const float v = sel_val[j];
    const float* wr = Wdec + (size_t)sel_idx[j] * Ddim;
    a0 += v * wr[t];
    a1 += v * wr[t + 256];
    a2 += v * wr[t + 512];
  }
  const float sd = std_arr[r], mv = mu_arr[r];
  float* rec = out_rec + (size_t)r * Ddim;
  rec[t]       = (a0 + pre_bias[t]) * sd + mv;
  rec[t + 256] = (a1 + pre_bias[t + 256]) * sd + mv;
  rec[t + 512] = (a2 + pre_bias[t + 512]) * sd + mv;
}

// ---------------------------------------------------------------- launch
extern "C" void kernel_launch(void* const* d_in, const int* in_sizes, int n_in,
                              void* d_out, int out_size, void* d_ws, size_t ws_size,
                              hipStream_t stream) {
  const float* x     = (const float*)d_in[0];
  const float* pre_b = (const float*)d_in[1];
  const float* lat_b = (const float*)d_in[2];
  const float* W_enc = (const float*)d_in[3];
  const float* W_dec = (const float*)d_in[4];

  float* out0 = (float*)d_out;                 // latents_pre_act [B,L]
  float* out1 = out0 + (size_t)Bdim * Ldim;    // latents         [B,L]
  float* out2 = out1 + (size_t)Bdim * Ldim;    // recons          [B,D]

  char* p = (char*)d_ws;
  __hip_bfloat16* xh = (__hip_bfloat16*)p; p += (size_t)Bdim * Ddim * 2;
  __hip_bfloat16* xl = (__hip_bfloat16*)p; p += (size_t)Bdim * Ddim * 2;
  __hip_bfloat16* Wh = (__hip_bfloat16*)p; p += (size_t)Ldim * Ddim * 2;
  __hip_bfloat16* Wl = (__hip_bfloat16*)p; p += (size_t)Ldim * Ddim * 2;
  float* xn32 = (float*)p;                 p += (size_t)Bdim * Ddim * 4;
  float* Wt32 = (float*)p;                 p += (size_t)Ldim * Ddim * 4;
  float* muv  = (float*)p;                 p += (size_t)Bdim * 4;
  float* sdv  = (float*)p;

  normalize_kernel<<<Bdim, 256, 0, stream>>>(x, pre_b, xh, xl, xn32, muv, sdv);
  wsplit_kernel<<<dim3(Ldim / 32, Ddim / 32), 256, 0, stream>>>(W_enc, Wh, Wl, Wt32);
  encode_gemm_kernel<<<dim3(Ldim / 128, Bdim / 128), 256, 0, stream>>>(
      xh, xl, Wh, Wl, lat_b, out0);
  topk_decode_kernel<<<Bdim, 256, 0, stream>>>(
      out0, xn32, Wt32, lat_b, W_dec, pre_b, muv, sdv, out1, out2);
}